// Round 9
// baseline (271.368 us; speedup 1.0000x reference)
//
#include <hip/hip_runtime.h>
#include <math.h>

#define B  2
#define L  4096
#define D  512
#define H  8
#define DH 64
#define BH (B * H)
#define K3 1536          // tripled-K layout kept for WpT (third copy unused now)
#define XPW 1024         // Xp width: [hi | lo]

typedef short s16x8 __attribute__((ext_vector_type(8)));
typedef float f32x4 __attribute__((ext_vector_type(4)));

#define AS1 __attribute__((address_space(1)))
#define AS3 __attribute__((address_space(3)))

__device__ __forceinline__ void lds_load16(const void* g, void* l) {
    __builtin_amdgcn_global_load_lds((const AS1 unsigned int*)g,
                                     (AS3 unsigned int*)l, 16, 0, 0);
}

__device__ __forceinline__ unsigned short f2bf(float x) {
    union { float f; unsigned u; } v; v.f = x;
    unsigned u = v.u;
    return (unsigned short)((u + 0x7fff + ((u >> 16) & 1)) >> 16);
}
__device__ __forceinline__ float bf2f(unsigned short h) {
    union { float f; unsigned u; } v; v.u = ((unsigned)h) << 16;
    return v.f;
}

#define MEMFENCE asm volatile("" ::: "memory")
__device__ __forceinline__ void wg_bar() {
    MEMFENCE;
    __builtin_amdgcn_s_barrier();
    MEMFENCE;
}

// ---------------------------------------------------------------------------
// Fused prep: blocks [0,192) = split_w; [192, 192+12288) = split_x.
// ---------------------------------------------------------------------------
__global__ __launch_bounds__(256)
void k_split(const float* __restrict__ q, const float* __restrict__ k,
             const float* __restrict__ v,
             const float* __restrict__ wq, const float* __restrict__ wk,
             const float* __restrict__ wv,
             unsigned short* __restrict__ Xp, unsigned short* __restrict__ WpT)
{
    const int tid = threadIdx.x;
    if (blockIdx.x < 192) {
        __shared__ float t[64][65];
        const int bx = blockIdx.x;
        const int e  = bx >> 6;
        const int k0 = (bx & 7) * 64;
        const int n0 = ((bx >> 3) & 7) * 64;
        const float* W = (e == 0) ? wq : (e == 1) ? wk : wv;

        for (int idx = tid; idx < 64 * 16; idx += 256) {
            const int i = idx >> 4, j4 = (idx & 15) << 2;
            *(float4*)&t[i][j4] = *(const float4*)(W + (size_t)(k0 + i) * 512 + n0 + j4);
        }
        __syncthreads();

        const int n_loc = tid >> 2;
        const int kq    = (tid & 3) << 4;
        unsigned short h[16], l[16];
        #pragma unroll
        for (int tt = 0; tt < 16; tt++) {
            const float x = t[kq + tt][n_loc];
            h[tt] = f2bf(x);
            l[tt] = f2bf(x - bf2f(h[tt]));
        }
        unsigned short* base = WpT + (size_t)e * 512 * K3 + (size_t)(n0 + n_loc) * K3 + k0 + kq;
        #pragma unroll
        for (int g4 = 0; g4 < 4; g4++) {
            ushort4 hv = make_ushort4(h[g4*4], h[g4*4+1], h[g4*4+2], h[g4*4+3]);
            ushort4 lv = make_ushort4(l[g4*4], l[g4*4+1], l[g4*4+2], l[g4*4+3]);
            *(ushort4*)(base + g4*4)        = hv;
            *(ushort4*)(base + 512 + g4*4)  = lv;
        }
    } else {
        const size_t g = (size_t)(blockIdx.x - 192) * 256 + tid;
        const size_t per = (size_t)8192 * 128;
        const int e = (int)(g / per);
        const size_t rem = g - (size_t)e * per;
        const int m  = (int)(rem >> 7);
        const int kq = (int)(rem & 127) << 2;

        const float* X = (e == 0) ? q : (e == 1) ? k : v;
        const float4 x = *(const float4*)(X + (size_t)m * 512 + kq);

        unsigned short h0 = f2bf(x.x), h1 = f2bf(x.y), h2 = f2bf(x.z), h3 = f2bf(x.w);
        unsigned short* dst = Xp + (size_t)e * 8192 * XPW + (size_t)m * XPW + kq;
        *(ushort4*)(dst) = make_ushort4(h0, h1, h2, h3);
        if (e != 2) {
            unsigned short l0 = f2bf(x.x - bf2f(h0)), l1 = f2bf(x.y - bf2f(h1));
            unsigned short l2 = f2bf(x.z - bf2f(h2)), l3 = f2bf(x.w - bf2f(h3));
            *(ushort4*)(dst + 512) = make_ushort4(l0, l1, l2, l3);
        }
    }
}

// ---------------------------------------------------------------------------
// Kernel 1: FUSED bf16-split MFMA GEMM, 128x128 tile, 4 waves, 64 KiB LDS ->
// TWO blocks resident per CU.  Per BK-32 chunk: stage {Ah, Al, Bh, Bl}
// [128][32], compute hi.hi + hi.lo + lo.hi with register-resident fragments.
// Swizzle: 16B-chunk pos ^= ((row>>1)&3) on stage-source and read.
// V (e==2): hi-only.
// ---------------------------------------------------------------------------
#define MFMA16 __builtin_amdgcn_mfma_f32_16x16x32_bf16

__global__ __launch_bounds__(256, 2)
void gemm_mfma(const unsigned short* __restrict__ Xp,
               const unsigned short* __restrict__ WpT,
               const float* __restrict__ bq, const float* __restrict__ bk,
               const float* __restrict__ bv,
               float* __restrict__ Qo, float* __restrict__ Ko,
               float* __restrict__ Vo)
{
    __shared__ __align__(16) unsigned short lds[32768];   // 64 KiB

    const int e = blockIdx.z;
    const float* bias = (e == 0) ? bq : (e == 1) ? bk : bv;
    float* C          = (e == 0) ? Qo : (e == 1) ? Ko : Vo;
    const unsigned short* Ag = Xp  + (size_t)e * 8192 * XPW;
    const unsigned short* Bg = WpT + (size_t)e * 512 * K3;

    const int tid  = threadIdx.x;
    const int lane = tid & 63;
    const int wid  = tid >> 6;            // 0..3
    const int wm   = wid & 1;             // 2 wave-rows  (64 rows each)
    const int wn   = wid >> 1;            // 2 wave-cols  (64 cols each)
    const int m0   = blockIdx.x * 128;
    const int n0g  = blockIdx.y * 128;

    const int srow = lane >> 2;                       // 0..15
    const int spos = lane & 3;
    const int sswz = (spos ^ ((srow >> 1) & 3)) << 3; // element offset
    const int row0 = wid * 32 + srow;                 // 0..127
    const int row1 = row0 + 16;

    const unsigned short* aH0 = Ag + (size_t)(m0 + row0) * XPW + sswz;
    const unsigned short* aH1 = Ag + (size_t)(m0 + row1) * XPW + sswz;
    const unsigned short* aL0 = aH0 + 512;
    const unsigned short* aL1 = aH1 + 512;
    const unsigned short* bH0 = Bg + (size_t)(n0g + row0) * K3 + sswz;
    const unsigned short* bH1 = Bg + (size_t)(n0g + row1) * K3 + sswz;
    const unsigned short* bL0 = bH0 + 512;
    const unsigned short* bL1 = bH1 + 512;

    const int wr0 = wid * 1024;
    const int wr1 = wr0 + 512;

    const int r16 = lane & 15, quad = lane >> 4;
    const int laneOff = r16 * 64 + ((quad ^ ((r16 >> 1) & 3)) << 4);  // bytes
    const char* ldsC = (const char*)lds;

    f32x4 acc[4][4];
    #pragma unroll
    for (int i = 0; i < 4; i++)
        #pragma unroll
        for (int j = 0; j < 4; j++)
            acc[i][j] = (f32x4){0.f, 0.f, 0.f, 0.f};

    const int NT = 16;                    // BK-32 chunks over K=512

    if (e != 2) {
        #define STAGE_QK(kk, nu) do {                                   \
            const int ka_ = (kk) * 32;                                  \
            unsigned short* dd_ = lds + (nu);                           \
            lds_load16(aH0 + ka_, dd_ + wr0);                           \
            lds_load16(aH1 + ka_, dd_ + wr1);                           \
            lds_load16(aL0 + ka_, dd_ + 4096  + wr0);                   \
            lds_load16(aL1 + ka_, dd_ + 4096  + wr1);                   \
            lds_load16(bH0 + ka_, dd_ + 8192  + wr0);                   \
            lds_load16(bH1 + ka_, dd_ + 8192  + wr1);                   \
            lds_load16(bL0 + ka_, dd_ + 12288 + wr0);                   \
            lds_load16(bL1 + ka_, dd_ + 12288 + wr1);                   \
        } while (0)

        STAGE_QK(0, 0);
        s16x8 aF[4], bh[4], bl[4];

        for (int t = 0; t < NT; ++t) {
            const int pa = (t & 1) << 15;          // compute-buffer bytes
            const int nu = (~t & 1) << 14;         // stage-buffer ushorts
            if (t + 1 < NT) {
                STAGE_QK(t + 1, nu);
                asm volatile("s_waitcnt vmcnt(8)" ::: "memory");  // chunk t landed
            } else {
                asm volatile("s_waitcnt vmcnt(0)" ::: "memory");
            }
            wg_bar();

            const char* base = ldsC + pa;
            const char* fAh = base + (wm * 64) * 64 + laneOff;
            const char* fAl = base + 8192  + (wm * 64) * 64 + laneOff;
            const char* fBh = base + 16384 + (wn * 64) * 64 + laneOff;
            const char* fBl = base + 24576 + (wn * 64) * 64 + laneOff;

            #pragma unroll
            for (int mq = 0; mq < 4; mq++) aF[mq] = *(const s16x8*)(fAh + mq * 1024);
            #pragma unroll
            for (int nq = 0; nq < 4; nq++) {
                bh[nq] = *(const s16x8*)(fBh + nq * 1024);
                bl[nq] = *(const s16x8*)(fBl + nq * 1024);
            }
            __builtin_amdgcn_s_setprio(1);
            #pragma unroll
            for (int mq = 0; mq < 4; mq++)
                #pragma unroll
                for (int nq = 0; nq < 4; nq++)
                    acc[mq][nq] = MFMA16(aF[mq], bh[nq], acc[mq][nq], 0, 0, 0);
            #pragma unroll
            for (int mq = 0; mq < 4; mq++)
                #pragma unroll
                for (int nq = 0; nq < 4; nq++)
                    acc[mq][nq] = MFMA16(aF[mq], bl[nq], acc[mq][nq], 0, 0, 0);
            __builtin_amdgcn_s_setprio(0);

            #pragma unroll
            for (int mq = 0; mq < 4; mq++) aF[mq] = *(const s16x8*)(fAl + mq * 1024);
            __builtin_amdgcn_s_setprio(1);
            #pragma unroll
            for (int mq = 0; mq < 4; mq++)
                #pragma unroll
                for (int nq = 0; nq < 4; nq++)
                    acc[mq][nq] = MFMA16(aF[mq], bh[nq], acc[mq][nq], 0, 0, 0);
            __builtin_amdgcn_s_setprio(0);
            wg_bar();
        }
    } else {
        #define STAGE_V(kk, nu) do {                                    \
            const int ka_ = (kk) * 32;                                  \
            unsigned short* dd_ = lds + (nu);                           \
            lds_load16(aH0 + ka_, dd_ + wr0);                           \
            lds_load16(aH1 + ka_, dd_ + wr1);                           \
            lds_load16(bH0 + ka_, dd_ + 8192 + wr0);                    \
            lds_load16(bH1 + ka_, dd_ + 8192 + wr1);                    \
        } while (0)

        STAGE_V(0, 0);
        s16x8 aF[4], bh[4];

        for (int t = 0; t < NT; ++t) {
            const int pa = (t & 1) << 15;
            const int nu = (~t & 1) << 14;
            if (t + 1 < NT) {
                STAGE_V(t + 1, nu);
                asm volatile("s_waitcnt vmcnt(4)" ::: "memory");
            } else {
                asm volatile("s_waitcnt vmcnt(0)" ::: "memory");
            }
            wg_bar();

            const char* base = ldsC + pa;
            const char* fAh = base + (wm * 64) * 64 + laneOff;
            const char* fBh = base + 16384 + (wn * 64) * 64 + laneOff;
            #pragma unroll
            for (int mq = 0; mq < 4; mq++) aF[mq] = *(const s16x8*)(fAh + mq * 1024);
            #pragma unroll
            for (int nq = 0; nq < 4; nq++) bh[nq] = *(const s16x8*)(fBh + nq * 1024);
            __builtin_amdgcn_s_setprio(1);
            #pragma unroll
            for (int mq = 0; mq < 4; mq++)
                #pragma unroll
                for (int nq = 0; nq < 4; nq++)
                    acc[mq][nq] = MFMA16(aF[mq], bh[nq], acc[mq][nq], 0, 0, 0);
            __builtin_amdgcn_s_setprio(0);
            wg_bar();
        }
    }

    // ---- epilogue
    #pragma unroll
    for (int nt = 0; nt < 4; nt++) {
        const int col = n0g + wn * 64 + nt * 16 + r16;
        const float bb = bias[col];
        #pragma unroll
        for (int mt = 0; mt < 4; mt++) {
            const int row0e = m0 + wm * 64 + mt * 16 + quad * 4;
            #pragma unroll
            for (int i = 0; i < 4; i++)
                C[(size_t)(row0e + i) * 512 + col] = acc[mt][nt][i] + bb;
        }
    }
}

// ---------------------------------------------------------------------------
// Fused: blocks [0,256) = chunk_sums; [256, 256+16384) = sample_m.
// (round-6 form restored: 256-thread blocks; the 1024-thread variant
// regressed 48->52.5 us, occupancy 45->41 -- CP-dispatch theory falsified)
// sample_m blocks XCD-SWIZZLED: bh = i & 15 -> bh%8 = XCD.
// ---------------------------------------------------------------------------
#define CH 64
__global__ __launch_bounds__(256)
void k_sample_chunks(const float* __restrict__ Q, const float* __restrict__ K,
                     const int* __restrict__ idx, float* __restrict__ m_out, int S,
                     const float* __restrict__ V, float* __restrict__ partial)
{
    const int tid = threadIdx.x;
    if (blockIdx.x < 256) {
        const int bid = blockIdx.x;
        const int c  = (bid & 15) * 4 + (tid >> 6);
        const int h  = (bid >> 4) & (H - 1);
        const int b  = bid >> 7;
        const int d  = tid & 63;
        const float* base = V + (size_t)b * L * D + h * DH + d + (size_t)(c * CH) * D;

        float vals[CH];
        #pragma unroll
        for (int i = 0; i < CH; i++) vals[i] = base[(size_t)i * D];

        float s0 = 0.f, s1 = 0.f, s2 = 0.f, s3 = 0.f;
        #pragma unroll
        for (int i = 0; i < CH; i += 4) {
            s0 += vals[i]; s1 += vals[i+1]; s2 += vals[i+2]; s3 += vals[i+3];
        }
        partial[((size_t)((b * H + h) * 64 + c)) * DH + d] = (s0 + s1) + (s2 + s3);
    } else {
        const int lane = tid & 63;
        const int wib  = tid >> 6;
        const int i    = blockIdx.x - 256;          // 0..16383
        const int bh   = i & 15;                    // XCD swizzle: bh fastest
        const int lg   = i >> 4;                    // l-group 0..1023
        const int l = lg * 4 + wib;
        const int h = bh & (H - 1);
        const int b = bh >> 3;
        const int widx = (bh << 12) | l;            // m_out index (b,h,l flat)

        const int r4 = lane >> 2;
        const int c4 = lane & 3;

        float4 qf[4];
        {
            const float4* qv = (const float4*)(Q + ((size_t)b * L + l) * D + h * DH);
            #pragma unroll
            for (int ii = 0; ii < 4; ii++) qf[ii] = qv[c4 + 4 * ii];
        }

        const float* Kb = K + (size_t)b * L * D + h * DH;
        const int* is = idx + (size_t)l * S;

        int  jj[3];
        bool ok[3];
        #pragma unroll
        for (int p = 0; p < 3; p++) {
            const int sp = p * 16 + r4;
            ok[p] = sp < S;
            jj[p] = ok[p] ? is[sp] : 0;
        }
        float4 kv[3][4];
        #pragma unroll
        for (int p = 0; p < 3; p++) {
            const float4* Krow = (const float4*)(Kb + (size_t)jj[p] * D);
            #pragma unroll
            for (int ii = 0; ii < 4; ii++) kv[p][ii] = Krow[c4 + 4 * ii];
        }

        float vmax = -INFINITY, vsum = 0.f;
        #pragma unroll
        for (int p = 0; p < 3; p++) {
            float dot = 0.f;
            #pragma unroll
            for (int ii = 0; ii < 4; ii++) {
                const float4 kvv = kv[p][ii];
                const float4 qq = qf[ii];
                dot += qq.x * kvv.x + qq.y * kvv.y + qq.z * kvv.z + qq.w * kvv.w;
            }
            dot += __shfl_xor(dot, 1, 64);
            dot += __shfl_xor(dot, 2, 64);   // full dot now in all 4 lanes of quad
            if (ok[p]) {
                vmax = fmaxf(vmax, dot);
                if (c4 == 0) vsum += dot;
            }
        }
        #pragma unroll
        for (int off = 32; off >= 4; off >>= 1) {
            vmax = fmaxf(vmax, __shfl_xor(vmax, off, 64));
            vsum += __shfl_xor(vsum, off, 64);
        }
        if (lane == 0) m_out[widx] = vmax - vsum * (1.0f / (float)L);
    }
}

// ---------------------------------------------------------------------------
// Kernel 3: exact top-NT via 4-level byte radix-select. One block per (b,h).
// Also zeroes sums[] and writes the selected-row flag array.
// ---------------------------------------------------------------------------
__global__ __launch_bounds__(256)
void topk_kernel(const float* __restrict__ m_in, int* __restrict__ m_top,
                 float* __restrict__ sums, int* __restrict__ flags, int NT)
{
    __shared__ unsigned hist[256];
    __shared__ unsigned sfx[257];
    __shared__ int sh_b, sh_rem;
    __shared__ int cnt_gt, cnt_eq;
    __shared__ int eqlist[128];

    const float* m = m_in + (size_t)blockIdx.x * L;
    const int tid = threadIdx.x;
    int* out = m_top + blockIdx.x * NT;
    int* fl  = flags + (size_t)blockIdx.x * L;

    if (tid < NT) sums[blockIdx.x * NT + tid] = 0.f;
    for (int i = tid; i < L; i += 256) fl[i] = 0;

    unsigned uv[16];
    #pragma unroll
    for (int k = 0; k < 16; k++) {
        const float f = m[tid + k * 256];
        const unsigned x = __float_as_uint(f);
        uv[k] = (x & 0x80000000u) ? ~x : (x | 0x80000000u);
    }

    unsigned prefix = 0;
    int rem = NT;

    for (int level = 0; level < 4; level++) {
        const int shift = 24 - level * 8;
        hist[tid] = 0;
        if (tid == 0) { cnt_gt = 0; cnt_eq = 0; }
        __syncthreads();
        #pragma unroll
        for (int k = 0; k < 16; k++) {
            const bool part = (level == 0) || ((uv[k] >> (shift + 8)) == prefix);
            if (part) atomicAdd(&hist[(uv[k] >> shift) & 255], 1u);
        }
        __syncthreads();
        if (tid < 64) {
            const unsigned s0 = hist[4*tid+0], s1 = hist[4*tid+1];
            const unsigned s2 = hist[4*tid+2], s3 = hist[4*tid+3];
            const unsigned loc = s0 + s1 + s2 + s3;
            unsigned suf = loc;
            #pragma unroll
            for (int off = 1; off < 64; off <<= 1) {
                const unsigned t = __shfl_down(suf, off, 64);
                if (tid + off < 64) suf += t;
            }
            const unsigned tail = suf - loc;
            sfx[4*tid+3] = tail + s3;
            sfx[4*tid+2] = tail + s3 + s2;
            sfx[4*tid+1] = tail + s3 + s2 + s1;
            sfx[4*tid+0] = suf;
            if (tid == 0) sfx[256] = 0;
        }
        __syncthreads();
        if (sfx[tid + 1] < (unsigned)rem && (unsigned)rem <= sfx[tid]) {
            sh_b   = tid;
            sh_rem = rem - (int)sfx[tid + 1];
        }
        __syncthreads();
        prefix = (prefix << 8) | (unsigned)sh_b;
        rem    = sh_rem;
        __syncthreads();
    }

    const unsigned T = prefix;
    const int n_gt = NT - rem;

    #pragma unroll
    for (int k = 0; k < 16; k++) {
        if (uv[k] > T) {
            const int pos = atomicAdd(&cnt_gt, 1);
            out[pos] = tid + k * 256;
        } else if (uv[k] == T) {
            const int pos = atomicAdd(&cnt_eq, 1);
            if (pos < 128) eqlist[pos] = tid + k * 256;
        }
    }
    __syncthreads();
    if (tid == 0) {
        int n = cnt_eq < 128 ? cnt_eq : 128;
        for (int r = 0; r < rem; r++) {
            int best = 0x7fffffff, bi = 0;
            for (int i = 0; i < n; i++)
                if (eqlist[i] < best) { best = eqlist[i]; bi = i; }
            out[n_gt + r] = best;
            eqlist[bi] = 0x7fffffff;
        }
    }
    __syncthreads();
    if (tid < NT) fl[out[tid]] = 1;
}

// ---------------------------------------------------------------------------
// Fused: blocks [0,256) = cumsum_write; [256, 256+384) = attn_scores.
// (round-6 form restored: 512-j scores blocks; the 256-j variant regressed)
// ---------------------------------------------------------------------------
__global__ __launch_bounds__(256)
void k_cumsum_scores(const float* __restrict__ V, const float* __restrict__ partial,
                     const int* __restrict__ flags, float* __restrict__ out,
                     const float* __restrict__ Q, const float* __restrict__ K,
                     const int* __restrict__ m_top, float* __restrict__ scores,
                     float* __restrict__ sums, int NT)
{
    const int tid = threadIdx.x;
    if (blockIdx.x < 256) {
        const int bid = blockIdx.x;
        const int c  = (bid & 15) * 4 + (tid >> 6);
        const int h  = (bid >> 4) & (H - 1);
        const int b  = bid >> 7;
        const int d  = tid & 63;
        const size_t off = (size_t)b * L * D + h * DH + d + (size_t)(c * CH) * D;
        const float* base  = V   + off;
        float*       obase = out + off;
        const float* pb = partial + (size_t)((b * H + h) * 64) * DH + d;
        const int*   fp = flags + (size_t)(b * H + h) * L + c * CH;

        float vals[CH];
        #pragma unroll
        for (int i = 0; i < CH; i++) vals[i] = base[(size_t)i * D];

        float acc = 0.f;
        for (int cc = 0; cc < c; cc++) acc += pb[cc * DH];

        #pragma unroll
        for (int i = 0; i < CH; i++) {
            acc += vals[i];
            obase[(size_t)i * D] = fp[i] ? 0.f : acc;
        }
    } else {
        __shared__ float qsh[15][DH];
        __shared__ int   psh[15];

        const int rem2 = blockIdx.x - 256;
        const int bh = rem2 / 24;
        const int r2 = rem2 % 24;
        const int ug = r2 >> 3;
        const int jc = r2 & 7;
        const int h  = bh & (H - 1);
        const int b  = bh >> 3;
        const int j0 = jc * 512;

        for (int i = tid; i < 15 * DH; i += 256) {
            const int u = i >> 6, d = i & 63;
            const int p = m_top[bh * NT + ug * 15 + u];
            if (d == 0) psh[u] = p;
            qsh[u][d] = Q[((size_t)b * L + p) * D + h * DH + d];
        }
        __syncthreads();

        const float* Kb = K + (size_t)b * L * D + h * DH;
        const int ja = j0 + tid;
        const int jb = ja + 256;
        float4 k0[16], k1[16];
        {
            const float4* ra = (const float4*)(Kb + (size_t)ja * D);
            const float4* rb = (const float4*)(Kb + (size_t)jb * D);
            #pragma unroll
            for (int i = 0; i < 16; i++) { k0[i] = ra[i]; k1[i] = rb[i]; }
        }

        for (int u = 0; u < 15; u++) {
            const int p = psh[u];
            const float4* qv = (const float4*)qsh[u];
            float d0 = 0.f, d1 = 0.f;
            #pragma unroll
            for (int i = 0; i < 16; i++) {
                const float4 q4 = qv[i];
                d0 += q4.x * k0[i].x + q4.y * k0[i].y + q4.z * k0[i].z + q4.w * k0[i].w;
                d1 += q4.x * k1[i].x + q4.y * k1[i].y + q4.z * k1[i].z + q4.w * k1[i].w;
            }
            const float e0 = (ja <= p) ? __expf(d0 * 0.125f) : 0.f;
            const float e1 = (jb <= p) ? __expf(d1 * 0.125f) : 0.f;
            float* srow = scores + (size_t)(bh * NT + ug * 15 + u) * L;
            srow[ja] = e0;
            srow[jb] = e1;
            float t = e0 + e1;
            #pragma unroll
            for (int off = 32; off; off >>= 1) t += __shfl_xor(t, off, 64);
            if ((tid & 63) == 0) atomicAdd(&sums[bh * NT + ug * 15 + u], t);
        }
    }
}

// ---------------------------------------------------------------------------
// Kernel 6c: weighted-V accumulate.  RESTRUCTURED: 16 j-segments of 256
// (was 64 segments of 64) with per-u register accumulators -- the old form
// issued ~1.5M fp32 atomics ~33-deep onto 184 KB of addresses (same
// coherence-point serialization that sank round-3's split-K).  Now each
// block accumulates 4x64-column chunks in registers and does ONE atomicAdd
// per (u,d): 4x fewer atomics, depth ~8.  u-accumulators are fully
// unrolled (static indices) to stay in VGPRs.
// ---------------------------------------------------------------------------
__global__ __launch_bounds__(256)
void attn_wv(const float* __restrict__ scores, const float* __restrict__ V,
             const int* __restrict__ m_top, const float* __restrict__ sums,
             float* __restrict__ out, int NT)
{
    __shared__ float ssh[45][64];
    __shared__ float sinv[45];
    __shared__ int   psh[45];

    const int bh = blockIdx.y;
    const int h  = bh & (H - 1);
    const int b  = bh >> 3;
    const int j0 = blockIdx.x * 256;      // 16 segments of 256
    const int tid = threadIdx.x;
    const int d   = tid & 63;
    const int w   = tid >> 6;

    if (tid < NT) {
        psh[tid]  = m_top[bh * NT + tid];
        sinv[tid] = 1.0f / sums[bh * NT + tid];
    }
    __syncthreads();

    // thread (w,d) accumulates u = w + 4*i  (i < 12 covers u < 48 >= NT=45)
    float acc[12];
    #pragma unroll
    for (int i = 0; i < 12; i++) acc[i] = 0.f;

    const float* Vb = V + (size_t)b * L * D + h * DH + d;

    for (int ch = 0; ch < 4; ch++) {
        const int jc = j0 + ch * 64;
        __syncthreads();   // previous chunk's ssh consumers done
        for (int i = tid; i < NT * 64; i += 256) {
            const int u = i >> 6, j = i & 63;
            ssh[u][j] = scores[(size_t)(bh * NT + u) * L + jc + j] * sinv[u];
        }
        __syncthreads();

        float vreg[64];
        #pragma unroll
        for (int i = 0; i < 64; i++) vreg[i] = Vb[(size_t)(jc + i) * D];

        #pragma unroll
        for (int i = 0; i < 12; i++) {
            const int u = w + 4 * i;
            if (u < NT) {
                const float* wt = ssh[u];
                float a = acc[i];
                #pragma unroll
                for (int j = 0; j < 64; j++) a += wt[j] * vreg[j];
                acc[i] = a;
            }
        }
    }

    #pragma unroll
    for (int i = 0; i < 12; i++) {
        const int u = w + 4 * i;
        if (u < NT) {
            const int p = psh[u];
            if (p >= j0)   // contributions beyond p are exactly 0 (scores=0)
                atomicAdd(out + ((size_t)b * L + p) * D + h * DH + d, acc[i]);
        }
    }
}

// ---------------------------------------------------------------------------
extern "C" void kernel_launch(void* const* d_in, const int* in_sizes, int n_in,
                              void* d_out, int out_size, void* d_ws, size_t ws_size,
                              hipStream_t stream)
{
    const float* queries = (const float*)d_in[0];
    const float* keys    = (const float*)d_in[1];
    const float* values  = (const float*)d_in[2];
    const float* Wq      = (const float*)d_in[3];
    const float* bq      = (const float*)d_in[4];
    const float* Wk      = (const float*)d_in[5];
    const float* bk      = (const float*)d_in[6];
    const float* Wv      = (const float*)d_in[7];
    const float* bv      = (const float*)d_in[8];
    const int*   idx     = (const int*)d_in[9];
    float* out = (float*)d_out;

    const int S  = in_sizes[9] / L;   // sample_k = 45
    const int NT = S;

    const size_t NE = (size_t)B * L * D;
    float* Qb      = (float*)d_ws;
    float* Kb      = Qb + NE;
    float* Vb      = Kb + NE;
    float* m_buf   = Vb + NE;                           // BH*L
    float* cs_part = m_buf + (size_t)BH * L;            // BH*64*DH
    int*   m_top   = (int*)(cs_part + (size_t)BH * 64 * DH);
    float* sums    = (float*)(m_top + 1024);            // BH*NT
    int*   flags   = (int*)(sums + 1024);               // BH*L
    float* scores  = (float*)(flags + (size_t)BH * L);  // BH*NT*L
    unsigned short* Xp  = (unsigned short*)(scores + (size_t)BH * NT * L);
    unsigned short* WpT = Xp + (size_t)3 * 8192 * XPW;  // 3*512*K3

    k_split<<<192 + 3 * 8192 * 128 / 256, 256, 0, stream>>>(
        queries, keys, values, Wq, Wk, Wv, Xp, WpT);

    gemm_mfma<<<dim3(8192 / 128, 512 / 128, 3), 256, 0, stream>>>(
        Xp, WpT, bq, bk, bv, Qb, Kb, Vb);

    k_sample_chunks<<<256 + BH * L / 4, 256, 0, stream>>>(
        Qb, Kb, idx, m_buf, S, Vb, cs_part);

    topk_kernel<<<BH, 256, 0, stream>>>(m_buf, m_top, sums, flags, NT);

    k_cumsum_scores<<<256 + 384, 256, 0, stream>>>(
        Vb, cs_part, flags, out, Qb, Kb, m_top, scores, sums, NT);

    attn_wv<<<dim3(16, BH), 256, 0, stream>>>(scores, Vb, m_top, sums, out, NT);
}

// Round 10
// 245.424 us; speedup vs baseline: 1.1057x; 1.1057x over previous
//
#include <hip/hip_runtime.h>
#include <math.h>

#define B  2
#define L  4096
#define D  512
#define H  8
#define DH 64
#define BH (B * H)
#define K3 1536          // tripled-K layout kept for WpT (third copy unused now)
#define XPW 1024         // Xp width: [hi | lo]

typedef short s16x8 __attribute__((ext_vector_type(8)));
typedef float f32x4 __attribute__((ext_vector_type(4)));

#define AS1 __attribute__((address_space(1)))
#define AS3 __attribute__((address_space(3)))

__device__ __forceinline__ void lds_load16(const void* g, void* l) {
    __builtin_amdgcn_global_load_lds((const AS1 unsigned int*)g,
                                     (AS3 unsigned int*)l, 16, 0, 0);
}

__device__ __forceinline__ unsigned short f2bf(float x) {
    union { float f; unsigned u; } v; v.f = x;
    unsigned u = v.u;
    return (unsigned short)((u + 0x7fff + ((u >> 16) & 1)) >> 16);
}
__device__ __forceinline__ float bf2f(unsigned short h) {
    union { float f; unsigned u; } v; v.u = ((unsigned)h) << 16;
    return v.f;
}

#define MEMFENCE asm volatile("" ::: "memory")
__device__ __forceinline__ void wg_bar() {
    MEMFENCE;
    __builtin_amdgcn_s_barrier();
    MEMFENCE;
}

// ---------------------------------------------------------------------------
// Fused prep: blocks [0,192) = split_w; [192, 192+12288) = split_x.
// ---------------------------------------------------------------------------
__global__ __launch_bounds__(256)
void k_split(const float* __restrict__ q, const float* __restrict__ k,
             const float* __restrict__ v,
             const float* __restrict__ wq, const float* __restrict__ wk,
             const float* __restrict__ wv,
             unsigned short* __restrict__ Xp, unsigned short* __restrict__ WpT)
{
    const int tid = threadIdx.x;
    if (blockIdx.x < 192) {
        __shared__ float t[64][65];
        const int bx = blockIdx.x;
        const int e  = bx >> 6;
        const int k0 = (bx & 7) * 64;
        const int n0 = ((bx >> 3) & 7) * 64;
        const float* W = (e == 0) ? wq : (e == 1) ? wk : wv;

        for (int idx = tid; idx < 64 * 16; idx += 256) {
            const int i = idx >> 4, j4 = (idx & 15) << 2;
            *(float4*)&t[i][j4] = *(const float4*)(W + (size_t)(k0 + i) * 512 + n0 + j4);
        }
        __syncthreads();

        const int n_loc = tid >> 2;
        const int kq    = (tid & 3) << 4;
        unsigned short h[16], l[16];
        #pragma unroll
        for (int tt = 0; tt < 16; tt++) {
            const float x = t[kq + tt][n_loc];
            h[tt] = f2bf(x);
            l[tt] = f2bf(x - bf2f(h[tt]));
        }
        unsigned short* base = WpT + (size_t)e * 512 * K3 + (size_t)(n0 + n_loc) * K3 + k0 + kq;
        #pragma unroll
        for (int g4 = 0; g4 < 4; g4++) {
            ushort4 hv = make_ushort4(h[g4*4], h[g4*4+1], h[g4*4+2], h[g4*4+3]);
            ushort4 lv = make_ushort4(l[g4*4], l[g4*4+1], l[g4*4+2], l[g4*4+3]);
            *(ushort4*)(base + g4*4)        = hv;
            *(ushort4*)(base + 512 + g4*4)  = lv;
        }
    } else {
        const size_t g = (size_t)(blockIdx.x - 192) * 256 + tid;
        const size_t per = (size_t)8192 * 128;
        const int e = (int)(g / per);
        const size_t rem = g - (size_t)e * per;
        const int m  = (int)(rem >> 7);
        const int kq = (int)(rem & 127) << 2;

        const float* X = (e == 0) ? q : (e == 1) ? k : v;
        const float4 x = *(const float4*)(X + (size_t)m * 512 + kq);

        unsigned short h0 = f2bf(x.x), h1 = f2bf(x.y), h2 = f2bf(x.z), h3 = f2bf(x.w);
        unsigned short* dst = Xp + (size_t)e * 8192 * XPW + (size_t)m * XPW + kq;
        *(ushort4*)(dst) = make_ushort4(h0, h1, h2, h3);
        if (e != 2) {
            unsigned short l0 = f2bf(x.x - bf2f(h0)), l1 = f2bf(x.y - bf2f(h1));
            unsigned short l2 = f2bf(x.z - bf2f(h2)), l3 = f2bf(x.w - bf2f(h3));
            *(ushort4*)(dst + 512) = make_ushort4(l0, l1, l2, l3);
        }
    }
}

// ---------------------------------------------------------------------------
// Kernel 1: FUSED bf16-split MFMA GEMM, 128x128 tile, 4 waves, 64 KiB LDS ->
// TWO blocks resident per CU.  Per BK-32 chunk: stage {Ah, Al, Bh, Bl}
// [128][32], compute hi.hi + hi.lo + lo.hi with register-resident fragments.
// Swizzle: 16B-chunk pos ^= ((row>>1)&3) on stage-source and read.
// V (e==2): hi-only.
// ---------------------------------------------------------------------------
#define MFMA16 __builtin_amdgcn_mfma_f32_16x16x32_bf16

__global__ __launch_bounds__(256, 2)
void gemm_mfma(const unsigned short* __restrict__ Xp,
               const unsigned short* __restrict__ WpT,
               const float* __restrict__ bq, const float* __restrict__ bk,
               const float* __restrict__ bv,
               float* __restrict__ Qo, float* __restrict__ Ko,
               float* __restrict__ Vo)
{
    __shared__ __align__(16) unsigned short lds[32768];   // 64 KiB

    const int e = blockIdx.z;
    const float* bias = (e == 0) ? bq : (e == 1) ? bk : bv;
    float* C          = (e == 0) ? Qo : (e == 1) ? Ko : Vo;
    const unsigned short* Ag = Xp  + (size_t)e * 8192 * XPW;
    const unsigned short* Bg = WpT + (size_t)e * 512 * K3;

    const int tid  = threadIdx.x;
    const int lane = tid & 63;
    const int wid  = tid >> 6;            // 0..3
    const int wm   = wid & 1;             // 2 wave-rows  (64 rows each)
    const int wn   = wid >> 1;            // 2 wave-cols  (64 cols each)
    const int m0   = blockIdx.x * 128;
    const int n0g  = blockIdx.y * 128;

    const int srow = lane >> 2;                       // 0..15
    const int spos = lane & 3;
    const int sswz = (spos ^ ((srow >> 1) & 3)) << 3; // element offset
    const int row0 = wid * 32 + srow;                 // 0..127
    const int row1 = row0 + 16;

    const unsigned short* aH0 = Ag + (size_t)(m0 + row0) * XPW + sswz;
    const unsigned short* aH1 = Ag + (size_t)(m0 + row1) * XPW + sswz;
    const unsigned short* aL0 = aH0 + 512;
    const unsigned short* aL1 = aH1 + 512;
    const unsigned short* bH0 = Bg + (size_t)(n0g + row0) * K3 + sswz;
    const unsigned short* bH1 = Bg + (size_t)(n0g + row1) * K3 + sswz;
    const unsigned short* bL0 = bH0 + 512;
    const unsigned short* bL1 = bH1 + 512;

    const int wr0 = wid * 1024;
    const int wr1 = wr0 + 512;

    const int r16 = lane & 15, quad = lane >> 4;
    const int laneOff = r16 * 64 + ((quad ^ ((r16 >> 1) & 3)) << 4);  // bytes
    const char* ldsC = (const char*)lds;

    f32x4 acc[4][4];
    #pragma unroll
    for (int i = 0; i < 4; i++)
        #pragma unroll
        for (int j = 0; j < 4; j++)
            acc[i][j] = (f32x4){0.f, 0.f, 0.f, 0.f};

    const int NT = 16;                    // BK-32 chunks over K=512

    if (e != 2) {
        #define STAGE_QK(kk, nu) do {                                   \
            const int ka_ = (kk) * 32;                                  \
            unsigned short* dd_ = lds + (nu);                           \
            lds_load16(aH0 + ka_, dd_ + wr0);                           \
            lds_load16(aH1 + ka_, dd_ + wr1);                           \
            lds_load16(aL0 + ka_, dd_ + 4096  + wr0);                   \
            lds_load16(aL1 + ka_, dd_ + 4096  + wr1);                   \
            lds_load16(bH0 + ka_, dd_ + 8192  + wr0);                   \
            lds_load16(bH1 + ka_, dd_ + 8192  + wr1);                   \
            lds_load16(bL0 + ka_, dd_ + 12288 + wr0);                   \
            lds_load16(bL1 + ka_, dd_ + 12288 + wr1);                   \
        } while (0)

        STAGE_QK(0, 0);
        s16x8 aF[4], bh[4], bl[4];

        for (int t = 0; t < NT; ++t) {
            const int pa = (t & 1) << 15;          // compute-buffer bytes
            const int nu = (~t & 1) << 14;         // stage-buffer ushorts
            if (t + 1 < NT) {
                STAGE_QK(t + 1, nu);
                asm volatile("s_waitcnt vmcnt(8)" ::: "memory");  // chunk t landed
            } else {
                asm volatile("s_waitcnt vmcnt(0)" ::: "memory");
            }
            wg_bar();

            const char* base = ldsC + pa;
            const char* fAh = base + (wm * 64) * 64 + laneOff;
            const char* fAl = base + 8192  + (wm * 64) * 64 + laneOff;
            const char* fBh = base + 16384 + (wn * 64) * 64 + laneOff;
            const char* fBl = base + 24576 + (wn * 64) * 64 + laneOff;

            #pragma unroll
            for (int mq = 0; mq < 4; mq++) aF[mq] = *(const s16x8*)(fAh + mq * 1024);
            #pragma unroll
            for (int nq = 0; nq < 4; nq++) {
                bh[nq] = *(const s16x8*)(fBh + nq * 1024);
                bl[nq] = *(const s16x8*)(fBl + nq * 1024);
            }
            __builtin_amdgcn_s_setprio(1);
            #pragma unroll
            for (int mq = 0; mq < 4; mq++)
                #pragma unroll
                for (int nq = 0; nq < 4; nq++)
                    acc[mq][nq] = MFMA16(aF[mq], bh[nq], acc[mq][nq], 0, 0, 0);
            #pragma unroll
            for (int mq = 0; mq < 4; mq++)
                #pragma unroll
                for (int nq = 0; nq < 4; nq++)
                    acc[mq][nq] = MFMA16(aF[mq], bl[nq], acc[mq][nq], 0, 0, 0);
            __builtin_amdgcn_s_setprio(0);

            #pragma unroll
            for (int mq = 0; mq < 4; mq++) aF[mq] = *(const s16x8*)(fAl + mq * 1024);
            __builtin_amdgcn_s_setprio(1);
            #pragma unroll
            for (int mq = 0; mq < 4; mq++)
                #pragma unroll
                for (int nq = 0; nq < 4; nq++)
                    acc[mq][nq] = MFMA16(aF[mq], bh[nq], acc[mq][nq], 0, 0, 0);
            __builtin_amdgcn_s_setprio(0);
            wg_bar();
        }
    } else {
        #define STAGE_V(kk, nu) do {                                    \
            const int ka_ = (kk) * 32;                                  \
            unsigned short* dd_ = lds + (nu);                           \
            lds_load16(aH0 + ka_, dd_ + wr0);                           \
            lds_load16(aH1 + ka_, dd_ + wr1);                           \
            lds_load16(bH0 + ka_, dd_ + 8192 + wr0);                    \
            lds_load16(bH1 + ka_, dd_ + 8192 + wr1);                    \
        } while (0)

        STAGE_V(0, 0);
        s16x8 aF[4], bh[4];

        for (int t = 0; t < NT; ++t) {
            const int pa = (t & 1) << 15;
            const int nu = (~t & 1) << 14;
            if (t + 1 < NT) {
                STAGE_V(t + 1, nu);
                asm volatile("s_waitcnt vmcnt(4)" ::: "memory");
            } else {
                asm volatile("s_waitcnt vmcnt(0)" ::: "memory");
            }
            wg_bar();

            const char* base = ldsC + pa;
            const char* fAh = base + (wm * 64) * 64 + laneOff;
            const char* fBh = base + 16384 + (wn * 64) * 64 + laneOff;
            #pragma unroll
            for (int mq = 0; mq < 4; mq++) aF[mq] = *(const s16x8*)(fAh + mq * 1024);
            #pragma unroll
            for (int nq = 0; nq < 4; nq++) bh[nq] = *(const s16x8*)(fBh + nq * 1024);
            __builtin_amdgcn_s_setprio(1);
            #pragma unroll
            for (int mq = 0; mq < 4; mq++)
                #pragma unroll
                for (int nq = 0; nq < 4; nq++)
                    acc[mq][nq] = MFMA16(aF[mq], bh[nq], acc[mq][nq], 0, 0, 0);
            __builtin_amdgcn_s_setprio(0);
            wg_bar();
        }
    }

    // ---- epilogue
    #pragma unroll
    for (int nt = 0; nt < 4; nt++) {
        const int col = n0g + wn * 64 + nt * 16 + r16;
        const float bb = bias[col];
        #pragma unroll
        for (int mt = 0; mt < 4; mt++) {
            const int row0e = m0 + wm * 64 + mt * 16 + quad * 4;
            #pragma unroll
            for (int i = 0; i < 4; i++)
                C[(size_t)(row0e + i) * 512 + col] = acc[mt][nt][i] + bb;
        }
    }
}

// ---------------------------------------------------------------------------
// Fused: blocks [0,256) = chunk_sums; [256, 256+16384) = sample_m.
// sample_m blocks XCD-SWIZZLED: bh = i & 15 -> bh%8 = XCD.
// MLP FIX: VGPR_Count was 44 -- the 12 "batched" float4 gathers CANNOT be
// simultaneously live in 44 regs, so the compiler serialized them (~4-deep
// chain, latency exposed).  Now: 12 NAMED float4 destinations + a
// sched_barrier(0) between the last load and the first use -> all 12 loads
// issue back-to-back, one waitcnt, VGPR ~96 (cap 5 waves/SIMD, above the
// measured 45% occupancy so the cap doesn't bind).
// ---------------------------------------------------------------------------
#define CH 64
__global__ __launch_bounds__(256)
void k_sample_chunks(const float* __restrict__ Q, const float* __restrict__ K,
                     const int* __restrict__ idx, float* __restrict__ m_out, int S,
                     const float* __restrict__ V, float* __restrict__ partial)
{
    const int tid = threadIdx.x;
    if (blockIdx.x < 256) {
        const int bid = blockIdx.x;
        const int c  = (bid & 15) * 4 + (tid >> 6);
        const int h  = (bid >> 4) & (H - 1);
        const int b  = bid >> 7;
        const int d  = tid & 63;
        const float* base = V + (size_t)b * L * D + h * DH + d + (size_t)(c * CH) * D;

        float vals[CH];
        #pragma unroll
        for (int i = 0; i < CH; i++) vals[i] = base[(size_t)i * D];

        float s0 = 0.f, s1 = 0.f, s2 = 0.f, s3 = 0.f;
        #pragma unroll
        for (int i = 0; i < CH; i += 4) {
            s0 += vals[i]; s1 += vals[i+1]; s2 += vals[i+2]; s3 += vals[i+3];
        }
        partial[((size_t)((b * H + h) * 64 + c)) * DH + d] = (s0 + s1) + (s2 + s3);
    } else {
        const int lane = tid & 63;
        const int wib  = tid >> 6;
        const int i    = blockIdx.x - 256;          // 0..16383
        const int bh   = i & 15;                    // XCD swizzle: bh fastest
        const int lg   = i >> 4;                    // l-group 0..1023
        const int l = lg * 4 + wib;
        const int h = bh & (H - 1);
        const int b = bh >> 3;
        const int widx = (bh << 12) | l;            // m_out index (b,h,l flat)

        const int r4 = lane >> 2;
        const int c4 = lane & 3;

        float4 qf[4];
        {
            const float4* qv = (const float4*)(Q + ((size_t)b * L + l) * D + h * DH);
            #pragma unroll
            for (int ii = 0; ii < 4; ii++) qf[ii] = qv[c4 + 4 * ii];
        }

        const float* Kb = K + (size_t)b * L * D + h * DH;
        const int* is = idx + (size_t)l * S;

        int  jj[3];
        bool ok[3];
        #pragma unroll
        for (int p = 0; p < 3; p++) {
            const int sp = p * 16 + r4;
            ok[p] = sp < S;
            jj[p] = ok[p] ? is[sp] : 0;
        }
        const float4* r0 = (const float4*)(Kb + (size_t)jj[0] * D);
        const float4* r1 = (const float4*)(Kb + (size_t)jj[1] * D);
        const float4* r2 = (const float4*)(Kb + (size_t)jj[2] * D);

        // 12 named destinations: all loads issued, THEN a hard scheduling
        // fence so no dot computation is hoisted between them.
        float4 k00 = r0[c4],     k01 = r0[c4 + 4], k02 = r0[c4 + 8], k03 = r0[c4 + 12];
        float4 k10 = r1[c4],     k11 = r1[c4 + 4], k12 = r1[c4 + 8], k13 = r1[c4 + 12];
        float4 k20 = r2[c4],     k21 = r2[c4 + 4], k22 = r2[c4 + 8], k23 = r2[c4 + 12];
        __builtin_amdgcn_sched_barrier(0);

        float vmax = -INFINITY, vsum = 0.f;
        {
            float dot = 0.f;
            dot += qf[0].x * k00.x + qf[0].y * k00.y + qf[0].z * k00.z + qf[0].w * k00.w;
            dot += qf[1].x * k01.x + qf[1].y * k01.y + qf[1].z * k01.z + qf[1].w * k01.w;
            dot += qf[2].x * k02.x + qf[2].y * k02.y + qf[2].z * k02.z + qf[2].w * k02.w;
            dot += qf[3].x * k03.x + qf[3].y * k03.y + qf[3].z * k03.z + qf[3].w * k03.w;
            dot += __shfl_xor(dot, 1, 64);
            dot += __shfl_xor(dot, 2, 64);
            if (ok[0]) { vmax = fmaxf(vmax, dot); if (c4 == 0) vsum += dot; }
        }
        {
            float dot = 0.f;
            dot += qf[0].x * k10.x + qf[0].y * k10.y + qf[0].z * k10.z + qf[0].w * k10.w;
            dot += qf[1].x * k11.x + qf[1].y * k11.y + qf[1].z * k11.z + qf[1].w * k11.w;
            dot += qf[2].x * k12.x + qf[2].y * k12.y + qf[2].z * k12.z + qf[2].w * k12.w;
            dot += qf[3].x * k13.x + qf[3].y * k13.y + qf[3].z * k13.z + qf[3].w * k13.w;
            dot += __shfl_xor(dot, 1, 64);
            dot += __shfl_xor(dot, 2, 64);
            if (ok[1]) { vmax = fmaxf(vmax, dot); if (c4 == 0) vsum += dot; }
        }
        {
            float dot = 0.f;
            dot += qf[0].x * k20.x + qf[0].y * k20.y + qf[0].z * k20.z + qf[0].w * k20.w;
            dot += qf[1].x * k21.x + qf[1].y * k21.y + qf[1].z * k21.z + qf[1].w * k21.w;
            dot += qf[2].x * k22.x + qf[2].y * k22.y + qf[2].z * k22.z + qf[2].w * k22.w;
            dot += qf[3].x * k23.x + qf[3].y * k23.y + qf[3].z * k23.z + qf[3].w * k23.w;
            dot += __shfl_xor(dot, 1, 64);
            dot += __shfl_xor(dot, 2, 64);
            if (ok[2]) { vmax = fmaxf(vmax, dot); if (c4 == 0) vsum += dot; }
        }
        #pragma unroll
        for (int off = 32; off >= 4; off >>= 1) {
            vmax = fmaxf(vmax, __shfl_xor(vmax, off, 64));
            vsum += __shfl_xor(vsum, off, 64);
        }
        if (lane == 0) m_out[widx] = vmax - vsum * (1.0f / (float)L);
    }
}

// ---------------------------------------------------------------------------
// Kernel 3: exact top-NT via 4-level byte radix-select. One block per (b,h).
// Also zeroes sums[] and writes the selected-row flag array.
// ---------------------------------------------------------------------------
__global__ __launch_bounds__(256)
void topk_kernel(const float* __restrict__ m_in, int* __restrict__ m_top,
                 float* __restrict__ sums, int* __restrict__ flags, int NT)
{
    __shared__ unsigned hist[256];
    __shared__ unsigned sfx[257];
    __shared__ int sh_b, sh_rem;
    __shared__ int cnt_gt, cnt_eq;
    __shared__ int eqlist[128];

    const float* m = m_in + (size_t)blockIdx.x * L;
    const int tid = threadIdx.x;
    int* out = m_top + blockIdx.x * NT;
    int* fl  = flags + (size_t)blockIdx.x * L;

    if (tid < NT) sums[blockIdx.x * NT + tid] = 0.f;
    for (int i = tid; i < L; i += 256) fl[i] = 0;

    unsigned uv[16];
    #pragma unroll
    for (int k = 0; k < 16; k++) {
        const float f = m[tid + k * 256];
        const unsigned x = __float_as_uint(f);
        uv[k] = (x & 0x80000000u) ? ~x : (x | 0x80000000u);
    }

    unsigned prefix = 0;
    int rem = NT;

    for (int level = 0; level < 4; level++) {
        const int shift = 24 - level * 8;
        hist[tid] = 0;
        if (tid == 0) { cnt_gt = 0; cnt_eq = 0; }
        __syncthreads();
        #pragma unroll
        for (int k = 0; k < 16; k++) {
            const bool part = (level == 0) || ((uv[k] >> (shift + 8)) == prefix);
            if (part) atomicAdd(&hist[(uv[k] >> shift) & 255], 1u);
        }
        __syncthreads();
        if (tid < 64) {
            const unsigned s0 = hist[4*tid+0], s1 = hist[4*tid+1];
            const unsigned s2 = hist[4*tid+2], s3 = hist[4*tid+3];
            const unsigned loc = s0 + s1 + s2 + s3;
            unsigned suf = loc;
            #pragma unroll
            for (int off = 1; off < 64; off <<= 1) {
                const unsigned t = __shfl_down(suf, off, 64);
                if (tid + off < 64) suf += t;
            }
            const unsigned tail = suf - loc;
            sfx[4*tid+3] = tail + s3;
            sfx[4*tid+2] = tail + s3 + s2;
            sfx[4*tid+1] = tail + s3 + s2 + s1;
            sfx[4*tid+0] = suf;
            if (tid == 0) sfx[256] = 0;
        }
        __syncthreads();
        if (sfx[tid + 1] < (unsigned)rem && (unsigned)rem <= sfx[tid]) {
            sh_b   = tid;
            sh_rem = rem - (int)sfx[tid + 1];
        }
        __syncthreads();
        prefix = (prefix << 8) | (unsigned)sh_b;
        rem    = sh_rem;
        __syncthreads();
    }

    const unsigned T = prefix;
    const int n_gt = NT - rem;

    #pragma unroll
    for (int k = 0; k < 16; k++) {
        if (uv[k] > T) {
            const int pos = atomicAdd(&cnt_gt, 1);
            out[pos] = tid + k * 256;
        } else if (uv[k] == T) {
            const int pos = atomicAdd(&cnt_eq, 1);
            if (pos < 128) eqlist[pos] = tid + k * 256;
        }
    }
    __syncthreads();
    if (tid == 0) {
        int n = cnt_eq < 128 ? cnt_eq : 128;
        for (int r = 0; r < rem; r++) {
            int best = 0x7fffffff, bi = 0;
            for (int i = 0; i < n; i++)
                if (eqlist[i] < best) { best = eqlist[i]; bi = i; }
            out[n_gt + r] = best;
            eqlist[bi] = 0x7fffffff;
        }
    }
    __syncthreads();
    if (tid < NT) fl[out[tid]] = 1;
}

// ---------------------------------------------------------------------------
// Fused: blocks [0,256) = cumsum_write; [256, 256+384) = attn_scores.
// ---------------------------------------------------------------------------
__global__ __launch_bounds__(256)
void k_cumsum_scores(const float* __restrict__ V, const float* __restrict__ partial,
                     const int* __restrict__ flags, float* __restrict__ out,
                     const float* __restrict__ Q, const float* __restrict__ K,
                     const int* __restrict__ m_top, float* __restrict__ scores,
                     float* __restrict__ sums, int NT)
{
    const int tid = threadIdx.x;
    if (blockIdx.x < 256) {
        const int bid = blockIdx.x;
        const int c  = (bid & 15) * 4 + (tid >> 6);
        const int h  = (bid >> 4) & (H - 1);
        const int b  = bid >> 7;
        const int d  = tid & 63;
        const size_t off = (size_t)b * L * D + h * DH + d + (size_t)(c * CH) * D;
        const float* base  = V   + off;
        float*       obase = out + off;
        const float* pb = partial + (size_t)((b * H + h) * 64) * DH + d;
        const int*   fp = flags + (size_t)(b * H + h) * L + c * CH;

        float vals[CH];
        #pragma unroll
        for (int i = 0; i < CH; i++) vals[i] = base[(size_t)i * D];

        float acc = 0.f;
        for (int cc = 0; cc < c; cc++) acc += pb[cc * DH];

        #pragma unroll
        for (int i = 0; i < CH; i++) {
            acc += vals[i];
            obase[(size_t)i * D] = fp[i] ? 0.f : acc;
        }
    } else {
        __shared__ float qsh[15][DH];
        __shared__ int   psh[15];

        const int rem2 = blockIdx.x - 256;
        const int bh = rem2 / 24;
        const int r2 = rem2 % 24;
        const int ug = r2 >> 3;
        const int jc = r2 & 7;
        const int h  = bh & (H - 1);
        const int b  = bh >> 3;
        const int j0 = jc * 512;

        for (int i = tid; i < 15 * DH; i += 256) {
            const int u = i >> 6, d = i & 63;
            const int p = m_top[bh * NT + ug * 15 + u];
            if (d == 0) psh[u] = p;
            qsh[u][d] = Q[((size_t)b * L + p) * D + h * DH + d];
        }
        __syncthreads();

        const float* Kb = K + (size_t)b * L * D + h * DH;
        const int ja = j0 + tid;
        const int jb = ja + 256;
        float4 k0[16], k1[16];
        {
            const float4* ra = (const float4*)(Kb + (size_t)ja * D);
            const float4* rb = (const float4*)(Kb + (size_t)jb * D);
            #pragma unroll
            for (int i = 0; i < 16; i++) { k0[i] = ra[i]; k1[i] = rb[i]; }
        }

        for (int u = 0; u < 15; u++) {
            const int p = psh[u];
            const float4* qv = (const float4*)qsh[u];
            float d0 = 0.f, d1 = 0.f;
            #pragma unroll
            for (int i = 0; i < 16; i++) {
                const float4 q4 = qv[i];
                d0 += q4.x * k0[i].x + q4.y * k0[i].y + q4.z * k0[i].z + q4.w * k0[i].w;
                d1 += q4.x * k1[i].x + q4.y * k1[i].y + q4.z * k1[i].z + q4.w * k1[i].w;
            }
            const float e0 = (ja <= p) ? __expf(d0 * 0.125f) : 0.f;
            const float e1 = (jb <= p) ? __expf(d1 * 0.125f) : 0.f;
            float* srow = scores + (size_t)(bh * NT + ug * 15 + u) * L;
            srow[ja] = e0;
            srow[jb] = e1;
            float t = e0 + e1;
            #pragma unroll
            for (int off = 32; off; off >>= 1) t += __shfl_xor(t, off, 64);
            if ((tid & 63) == 0) atomicAdd(&sums[bh * NT + ug * 15 + u], t);
        }
    }
}

// ---------------------------------------------------------------------------
// Kernel 6c: weighted-V accumulate into flag-zeroed output rows via atomics.
// (round-6 version restored: 64-j blocks, 1024 blocks = 4/CU.  The 256-block
// register-accumulator variant regressed ~21us: traded mild atomic depth for
// a 4x occupancy loss on a latency-bound kernel.)
// ---------------------------------------------------------------------------
__global__ __launch_bounds__(256)
void attn_wv(const float* __restrict__ scores, const float* __restrict__ V,
             const int* __restrict__ m_top, const float* __restrict__ sums,
             float* __restrict__ out, int NT)
{
    __shared__ float ssh[45][64];
    __shared__ float sinv[45];
    __shared__ int   psh[45];

    const int bh = blockIdx.y;
    const int h  = bh & (H - 1);
    const int b  = bh >> 3;
    const int j0 = blockIdx.x * 64;
    const int tid = threadIdx.x;
    const int d   = tid & 63;
    const int w   = tid >> 6;

    if (tid < NT) {
        psh[tid]  = m_top[bh * NT + tid];
        sinv[tid] = 1.0f / sums[bh * NT + tid];
    }

    const float* Vb = V + (size_t)b * L * D + h * DH + d;
    float vreg[64];
    #pragma unroll
    for (int i = 0; i < 64; i++) vreg[i] = Vb[(size_t)(j0 + i) * D];

    __syncthreads();
    for (int i = tid; i < NT * 64; i += 256) {
        const int u = i >> 6, j = i & 63;
        ssh[u][j] = scores[(size_t)(bh * NT + u) * L + j0 + j] * sinv[u];
    }
    __syncthreads();

    for (int u = w; u < NT; u += 4) {
        const int p = psh[u];
        if (p < j0) continue;
        const float* wt = ssh[u];
        float acc = 0.f;
        #pragma unroll
        for (int i = 0; i < 64; i++) acc += wt[i] * vreg[i];
        atomicAdd(out + ((size_t)b * L + p) * D + h * DH + d, acc);
    }
}

// ---------------------------------------------------------------------------
extern "C" void kernel_launch(void* const* d_in, const int* in_sizes, int n_in,
                              void* d_out, int out_size, void* d_ws, size_t ws_size,
                              hipStream_t stream)
{
    const float* queries = (const float*)d_in[0];
    const float* keys    = (const float*)d_in[1];
    const float* values  = (const float*)d_in[2];
    const float* Wq      = (const float*)d_in[3];
    const float* bq      = (const float*)d_in[4];
    const float* Wk      = (const float*)d_in[5];
    const float* bk      = (const float*)d_in[6];
    const float* Wv      = (const float*)d_in[7];
    const float* bv      = (const float*)d_in[8];
    const int*   idx     = (const int*)d_in[9];
    float* out = (float*)d_out;

    const int S  = in_sizes[9] / L;   // sample_k = 45
    const int NT = S;

    const size_t NE = (size_t)B * L * D;
    float* Qb      = (float*)d_ws;
    float* Kb      = Qb + NE;
    float* Vb      = Kb + NE;
    float* m_buf   = Vb + NE;                           // BH*L
    float* cs_part = m_buf + (size_t)BH * L;            // BH*64*DH
    int*   m_top   = (int*)(cs_part + (size_t)BH * 64 * DH);
    float* sums    = (float*)(m_top + 1024);            // BH*NT
    int*   flags   = (int*)(sums + 1024);               // BH*L
    float* scores  = (float*)(flags + (size_t)BH * L);  // BH*NT*L
    unsigned short* Xp  = (unsigned short*)(scores + (size_t)BH * NT * L);
    unsigned short* WpT = Xp + (size_t)3 * 8192 * XPW;  // 3*512*K3

    k_split<<<192 + 3 * 8192 * 128 / 256, 256, 0, stream>>>(
        queries, keys, values, Wq, Wk, Wv, Xp, WpT);

    gemm_mfma<<<dim3(8192 / 128, 512 / 128, 3), 256, 0, stream>>>(
        Xp, WpT, bq, bk, bv, Qb, Kb, Vb);

    k_sample_chunks<<<256 + BH * L / 4, 256, 0, stream>>>(
        Qb, Kb, idx, m_buf, S, Vb, cs_part);

    topk_kernel<<<BH, 256, 0, stream>>>(m_buf, m_top, sums, flags, NT);

    k_cumsum_scores<<<256 + 384, 256, 0, stream>>>(
        Vb, cs_part, flags, out, Qb, Kb, m_top, scores, sums, NT);

    attn_wv<<<dim3(64, BH), 256, 0, stream>>>(scores, Vb, m_top, sums, out, NT);
}

// Round 11
// 232.701 us; speedup vs baseline: 1.1662x; 1.0547x over previous
//
#include <hip/hip_runtime.h>
#include <math.h>

#define B  2
#define L  4096
#define D  512
#define H  8
#define DH 64
#define BH (B * H)
#define K3 1536          // tripled-K layout kept for WpT (third copy unused now)
#define XPW 1024         // Xp width: [hi | lo]

typedef short s16x8 __attribute__((ext_vector_type(8)));
typedef float f32x4 __attribute__((ext_vector_type(4)));

#define AS1 __attribute__((address_space(1)))
#define AS3 __attribute__((address_space(3)))

__device__ __forceinline__ void lds_load16(const void* g, void* l) {
    __builtin_amdgcn_global_load_lds((const AS1 unsigned int*)g,
                                     (AS3 unsigned int*)l, 16, 0, 0);
}

__device__ __forceinline__ unsigned short f2bf(float x) {
    union { float f; unsigned u; } v; v.f = x;
    unsigned u = v.u;
    return (unsigned short)((u + 0x7fff + ((u >> 16) & 1)) >> 16);
}
__device__ __forceinline__ float bf2f(unsigned short h) {
    union { float f; unsigned u; } v; v.u = ((unsigned)h) << 16;
    return v.f;
}

#define MEMFENCE asm volatile("" ::: "memory")
__device__ __forceinline__ void wg_bar() {
    MEMFENCE;
    __builtin_amdgcn_s_barrier();
    MEMFENCE;
}

// ---------------------------------------------------------------------------
// Fused prep: blocks [0,192) = split_w; [192, 192+12288) = split_x.
// ---------------------------------------------------------------------------
__global__ __launch_bounds__(256)
void k_split(const float* __restrict__ q, const float* __restrict__ k,
             const float* __restrict__ v,
             const float* __restrict__ wq, const float* __restrict__ wk,
             const float* __restrict__ wv,
             unsigned short* __restrict__ Xp, unsigned short* __restrict__ WpT)
{
    const int tid = threadIdx.x;
    if (blockIdx.x < 192) {
        __shared__ float t[64][65];
        const int bx = blockIdx.x;
        const int e  = bx >> 6;
        const int k0 = (bx & 7) * 64;
        const int n0 = ((bx >> 3) & 7) * 64;
        const float* W = (e == 0) ? wq : (e == 1) ? wk : wv;

        for (int idx = tid; idx < 64 * 16; idx += 256) {
            const int i = idx >> 4, j4 = (idx & 15) << 2;
            *(float4*)&t[i][j4] = *(const float4*)(W + (size_t)(k0 + i) * 512 + n0 + j4);
        }
        __syncthreads();

        const int n_loc = tid >> 2;
        const int kq    = (tid & 3) << 4;
        unsigned short h[16], l[16];
        #pragma unroll
        for (int tt = 0; tt < 16; tt++) {
            const float x = t[kq + tt][n_loc];
            h[tt] = f2bf(x);
            l[tt] = f2bf(x - bf2f(h[tt]));
        }
        unsigned short* base = WpT + (size_t)e * 512 * K3 + (size_t)(n0 + n_loc) * K3 + k0 + kq;
        #pragma unroll
        for (int g4 = 0; g4 < 4; g4++) {
            ushort4 hv = make_ushort4(h[g4*4], h[g4*4+1], h[g4*4+2], h[g4*4+3]);
            ushort4 lv = make_ushort4(l[g4*4], l[g4*4+1], l[g4*4+2], l[g4*4+3]);
            *(ushort4*)(base + g4*4)        = hv;
            *(ushort4*)(base + 512 + g4*4)  = lv;
        }
    } else {
        const size_t g = (size_t)(blockIdx.x - 192) * 256 + tid;
        const size_t per = (size_t)8192 * 128;
        const int e = (int)(g / per);
        const size_t rem = g - (size_t)e * per;
        const int m  = (int)(rem >> 7);
        const int kq = (int)(rem & 127) << 2;

        const float* X = (e == 0) ? q : (e == 1) ? k : v;
        const float4 x = *(const float4*)(X + (size_t)m * 512 + kq);

        unsigned short h0 = f2bf(x.x), h1 = f2bf(x.y), h2 = f2bf(x.z), h3 = f2bf(x.w);
        unsigned short* dst = Xp + (size_t)e * 8192 * XPW + (size_t)m * XPW + kq;
        *(ushort4*)(dst) = make_ushort4(h0, h1, h2, h3);
        if (e != 2) {
            unsigned short l0 = f2bf(x.x - bf2f(h0)), l1 = f2bf(x.y - bf2f(h1));
            unsigned short l2 = f2bf(x.z - bf2f(h2)), l3 = f2bf(x.w - bf2f(h3));
            *(ushort4*)(dst + 512) = make_ushort4(l0, l1, l2, l3);
        }
    }
}

// ---------------------------------------------------------------------------
// Kernel 1: FUSED bf16-split MFMA GEMM, 128x128 tile, 4 waves, 64 KiB LDS ->
// TWO blocks resident per CU.  Per BK-32 chunk: stage {Ah, Al, Bh, Bl}
// [128][32], compute hi.hi + hi.lo + lo.hi with register-resident fragments.
// Swizzle: 16B-chunk pos ^= ((row>>1)&3) on stage-source and read.
// V (e==2): hi-only.
// ---------------------------------------------------------------------------
#define MFMA16 __builtin_amdgcn_mfma_f32_16x16x32_bf16

__global__ __launch_bounds__(256, 2)
void gemm_mfma(const unsigned short* __restrict__ Xp,
               const unsigned short* __restrict__ WpT,
               const float* __restrict__ bq, const float* __restrict__ bk,
               const float* __restrict__ bv,
               float* __restrict__ Qo, float* __restrict__ Ko,
               float* __restrict__ Vo)
{
    __shared__ __align__(16) unsigned short lds[32768];   // 64 KiB

    const int e = blockIdx.z;
    const float* bias = (e == 0) ? bq : (e == 1) ? bk : bv;
    float* C          = (e == 0) ? Qo : (e == 1) ? Ko : Vo;
    const unsigned short* Ag = Xp  + (size_t)e * 8192 * XPW;
    const unsigned short* Bg = WpT + (size_t)e * 512 * K3;

    const int tid  = threadIdx.x;
    const int lane = tid & 63;
    const int wid  = tid >> 6;            // 0..3
    const int wm   = wid & 1;             // 2 wave-rows  (64 rows each)
    const int wn   = wid >> 1;            // 2 wave-cols  (64 cols each)
    const int m0   = blockIdx.x * 128;
    const int n0g  = blockIdx.y * 128;

    const int srow = lane >> 2;                       // 0..15
    const int spos = lane & 3;
    const int sswz = (spos ^ ((srow >> 1) & 3)) << 3; // element offset
    const int row0 = wid * 32 + srow;                 // 0..127
    const int row1 = row0 + 16;

    const unsigned short* aH0 = Ag + (size_t)(m0 + row0) * XPW + sswz;
    const unsigned short* aH1 = Ag + (size_t)(m0 + row1) * XPW + sswz;
    const unsigned short* aL0 = aH0 + 512;
    const unsigned short* aL1 = aH1 + 512;
    const unsigned short* bH0 = Bg + (size_t)(n0g + row0) * K3 + sswz;
    const unsigned short* bH1 = Bg + (size_t)(n0g + row1) * K3 + sswz;
    const unsigned short* bL0 = bH0 + 512;
    const unsigned short* bL1 = bH1 + 512;

    const int wr0 = wid * 1024;
    const int wr1 = wr0 + 512;

    const int r16 = lane & 15, quad = lane >> 4;
    const int laneOff = r16 * 64 + ((quad ^ ((r16 >> 1) & 3)) << 4);  // bytes
    const char* ldsC = (const char*)lds;

    f32x4 acc[4][4];
    #pragma unroll
    for (int i = 0; i < 4; i++)
        #pragma unroll
        for (int j = 0; j < 4; j++)
            acc[i][j] = (f32x4){0.f, 0.f, 0.f, 0.f};

    const int NT = 16;                    // BK-32 chunks over K=512

    if (e != 2) {
        #define STAGE_QK(kk, nu) do {                                   \
            const int ka_ = (kk) * 32;                                  \
            unsigned short* dd_ = lds + (nu);                           \
            lds_load16(aH0 + ka_, dd_ + wr0);                           \
            lds_load16(aH1 + ka_, dd_ + wr1);                           \
            lds_load16(aL0 + ka_, dd_ + 4096  + wr0);                   \
            lds_load16(aL1 + ka_, dd_ + 4096  + wr1);                   \
            lds_load16(bH0 + ka_, dd_ + 8192  + wr0);                   \
            lds_load16(bH1 + ka_, dd_ + 8192  + wr1);                   \
            lds_load16(bL0 + ka_, dd_ + 12288 + wr0);                   \
            lds_load16(bL1 + ka_, dd_ + 12288 + wr1);                   \
        } while (0)

        STAGE_QK(0, 0);
        s16x8 aF[4], bh[4], bl[4];

        for (int t = 0; t < NT; ++t) {
            const int pa = (t & 1) << 15;          // compute-buffer bytes
            const int nu = (~t & 1) << 14;         // stage-buffer ushorts
            if (t + 1 < NT) {
                STAGE_QK(t + 1, nu);
                asm volatile("s_waitcnt vmcnt(8)" ::: "memory");  // chunk t landed
            } else {
                asm volatile("s_waitcnt vmcnt(0)" ::: "memory");
            }
            wg_bar();

            const char* base = ldsC + pa;
            const char* fAh = base + (wm * 64) * 64 + laneOff;
            const char* fAl = base + 8192  + (wm * 64) * 64 + laneOff;
            const char* fBh = base + 16384 + (wn * 64) * 64 + laneOff;
            const char* fBl = base + 24576 + (wn * 64) * 64 + laneOff;

            #pragma unroll
            for (int mq = 0; mq < 4; mq++) aF[mq] = *(const s16x8*)(fAh + mq * 1024);
            #pragma unroll
            for (int nq = 0; nq < 4; nq++) {
                bh[nq] = *(const s16x8*)(fBh + nq * 1024);
                bl[nq] = *(const s16x8*)(fBl + nq * 1024);
            }
            __builtin_amdgcn_s_setprio(1);
            #pragma unroll
            for (int mq = 0; mq < 4; mq++)
                #pragma unroll
                for (int nq = 0; nq < 4; nq++)
                    acc[mq][nq] = MFMA16(aF[mq], bh[nq], acc[mq][nq], 0, 0, 0);
            #pragma unroll
            for (int mq = 0; mq < 4; mq++)
                #pragma unroll
                for (int nq = 0; nq < 4; nq++)
                    acc[mq][nq] = MFMA16(aF[mq], bl[nq], acc[mq][nq], 0, 0, 0);
            __builtin_amdgcn_s_setprio(0);

            #pragma unroll
            for (int mq = 0; mq < 4; mq++) aF[mq] = *(const s16x8*)(fAl + mq * 1024);
            __builtin_amdgcn_s_setprio(1);
            #pragma unroll
            for (int mq = 0; mq < 4; mq++)
                #pragma unroll
                for (int nq = 0; nq < 4; nq++)
                    acc[mq][nq] = MFMA16(aF[mq], bh[nq], acc[mq][nq], 0, 0, 0);
            __builtin_amdgcn_s_setprio(0);
            wg_bar();
        }
    } else {
        #define STAGE_V(kk, nu) do {                                    \
            const int ka_ = (kk) * 32;                                  \
            unsigned short* dd_ = lds + (nu);                           \
            lds_load16(aH0 + ka_, dd_ + wr0);                           \
            lds_load16(aH1 + ka_, dd_ + wr1);                           \
            lds_load16(bH0 + ka_, dd_ + 8192 + wr0);                    \
            lds_load16(bH1 + ka_, dd_ + 8192 + wr1);                    \
        } while (0)

        STAGE_V(0, 0);
        s16x8 aF[4], bh[4];

        for (int t = 0; t < NT; ++t) {
            const int pa = (t & 1) << 15;
            const int nu = (~t & 1) << 14;
            if (t + 1 < NT) {
                STAGE_V(t + 1, nu);
                asm volatile("s_waitcnt vmcnt(4)" ::: "memory");
            } else {
                asm volatile("s_waitcnt vmcnt(0)" ::: "memory");
            }
            wg_bar();

            const char* base = ldsC + pa;
            const char* fAh = base + (wm * 64) * 64 + laneOff;
            const char* fBh = base + 16384 + (wn * 64) * 64 + laneOff;
            #pragma unroll
            for (int mq = 0; mq < 4; mq++) aF[mq] = *(const s16x8*)(fAh + mq * 1024);
            #pragma unroll
            for (int nq = 0; nq < 4; nq++) bh[nq] = *(const s16x8*)(fBh + nq * 1024);
            __builtin_amdgcn_s_setprio(1);
            #pragma unroll
            for (int mq = 0; mq < 4; mq++)
                #pragma unroll
                for (int nq = 0; nq < 4; nq++)
                    acc[mq][nq] = MFMA16(aF[mq], bh[nq], acc[mq][nq], 0, 0, 0);
            __builtin_amdgcn_s_setprio(0);
            wg_bar();
        }
    }

    // ---- epilogue
    #pragma unroll
    for (int nt = 0; nt < 4; nt++) {
        const int col = n0g + wn * 64 + nt * 16 + r16;
        const float bb = bias[col];
        #pragma unroll
        for (int mt = 0; mt < 4; mt++) {
            const int row0e = m0 + wm * 64 + mt * 16 + quad * 4;
            #pragma unroll
            for (int i = 0; i < 4; i++)
                C[(size_t)(row0e + i) * 512 + col] = acc[mt][nt][i] + bb;
        }
    }
}

// ---------------------------------------------------------------------------
// Fused: blocks [0,256) = chunk_sums; [256, 256+16384) = sample_m.
// sample_m blocks XCD-SWIZZLED: bh = i & 15 -> bh%8 = XCD.
// (named-load form kept; measured neutral vs the array form, VGPR 44)
// ---------------------------------------------------------------------------
#define CH 64
__global__ __launch_bounds__(256)
void k_sample_chunks(const float* __restrict__ Q, const float* __restrict__ K,
                     const int* __restrict__ idx, float* __restrict__ m_out, int S,
                     const float* __restrict__ V, float* __restrict__ partial)
{
    const int tid = threadIdx.x;
    if (blockIdx.x < 256) {
        const int bid = blockIdx.x;
        const int c  = (bid & 15) * 4 + (tid >> 6);
        const int h  = (bid >> 4) & (H - 1);
        const int b  = bid >> 7;
        const int d  = tid & 63;
        const float* base = V + (size_t)b * L * D + h * DH + d + (size_t)(c * CH) * D;

        float vals[CH];
        #pragma unroll
        for (int i = 0; i < CH; i++) vals[i] = base[(size_t)i * D];

        float s0 = 0.f, s1 = 0.f, s2 = 0.f, s3 = 0.f;
        #pragma unroll
        for (int i = 0; i < CH; i += 4) {
            s0 += vals[i]; s1 += vals[i+1]; s2 += vals[i+2]; s3 += vals[i+3];
        }
        partial[((size_t)((b * H + h) * 64 + c)) * DH + d] = (s0 + s1) + (s2 + s3);
    } else {
        const int lane = tid & 63;
        const int wib  = tid >> 6;
        const int i    = blockIdx.x - 256;          // 0..16383
        const int bh   = i & 15;                    // XCD swizzle: bh fastest
        const int lg   = i >> 4;                    // l-group 0..1023
        const int l = lg * 4 + wib;
        const int h = bh & (H - 1);
        const int b = bh >> 3;
        const int widx = (bh << 12) | l;            // m_out index (b,h,l flat)

        const int r4 = lane >> 2;
        const int c4 = lane & 3;

        float4 qf[4];
        {
            const float4* qv = (const float4*)(Q + ((size_t)b * L + l) * D + h * DH);
            #pragma unroll
            for (int ii = 0; ii < 4; ii++) qf[ii] = qv[c4 + 4 * ii];
        }

        const float* Kb = K + (size_t)b * L * D + h * DH;
        const int* is = idx + (size_t)l * S;

        int  jj[3];
        bool ok[3];
        #pragma unroll
        for (int p = 0; p < 3; p++) {
            const int sp = p * 16 + r4;
            ok[p] = sp < S;
            jj[p] = ok[p] ? is[sp] : 0;
        }
        const float4* r0 = (const float4*)(Kb + (size_t)jj[0] * D);
        const float4* r1 = (const float4*)(Kb + (size_t)jj[1] * D);
        const float4* r2 = (const float4*)(Kb + (size_t)jj[2] * D);

        float4 k00 = r0[c4],     k01 = r0[c4 + 4], k02 = r0[c4 + 8], k03 = r0[c4 + 12];
        float4 k10 = r1[c4],     k11 = r1[c4 + 4], k12 = r1[c4 + 8], k13 = r1[c4 + 12];
        float4 k20 = r2[c4],     k21 = r2[c4 + 4], k22 = r2[c4 + 8], k23 = r2[c4 + 12];
        __builtin_amdgcn_sched_barrier(0);

        float vmax = -INFINITY, vsum = 0.f;
        {
            float dot = 0.f;
            dot += qf[0].x * k00.x + qf[0].y * k00.y + qf[0].z * k00.z + qf[0].w * k00.w;
            dot += qf[1].x * k01.x + qf[1].y * k01.y + qf[1].z * k01.z + qf[1].w * k01.w;
            dot += qf[2].x * k02.x + qf[2].y * k02.y + qf[2].z * k02.z + qf[2].w * k02.w;
            dot += qf[3].x * k03.x + qf[3].y * k03.y + qf[3].z * k03.z + qf[3].w * k03.w;
            dot += __shfl_xor(dot, 1, 64);
            dot += __shfl_xor(dot, 2, 64);
            if (ok[0]) { vmax = fmaxf(vmax, dot); if (c4 == 0) vsum += dot; }
        }
        {
            float dot = 0.f;
            dot += qf[0].x * k10.x + qf[0].y * k10.y + qf[0].z * k10.z + qf[0].w * k10.w;
            dot += qf[1].x * k11.x + qf[1].y * k11.y + qf[1].z * k11.z + qf[1].w * k11.w;
            dot += qf[2].x * k12.x + qf[2].y * k12.y + qf[2].z * k12.z + qf[2].w * k12.w;
            dot += qf[3].x * k13.x + qf[3].y * k13.y + qf[3].z * k13.z + qf[3].w * k13.w;
            dot += __shfl_xor(dot, 1, 64);
            dot += __shfl_xor(dot, 2, 64);
            if (ok[1]) { vmax = fmaxf(vmax, dot); if (c4 == 0) vsum += dot; }
        }
        {
            float dot = 0.f;
            dot += qf[0].x * k20.x + qf[0].y * k20.y + qf[0].z * k20.z + qf[0].w * k20.w;
            dot += qf[1].x * k21.x + qf[1].y * k21.y + qf[1].z * k21.z + qf[1].w * k21.w;
            dot += qf[2].x * k22.x + qf[2].y * k22.y + qf[2].z * k22.z + qf[2].w * k22.w;
            dot += qf[3].x * k23.x + qf[3].y * k23.y + qf[3].z * k23.z + qf[3].w * k23.w;
            dot += __shfl_xor(dot, 1, 64);
            dot += __shfl_xor(dot, 2, 64);
            if (ok[2]) { vmax = fmaxf(vmax, dot); if (c4 == 0) vsum += dot; }
        }
        #pragma unroll
        for (int off = 32; off >= 4; off >>= 1) {
            vmax = fmaxf(vmax, __shfl_xor(vmax, off, 64));
            vsum += __shfl_xor(vsum, off, 64);
        }
        if (lane == 0) m_out[widx] = vmax - vsum * (1.0f / (float)L);
    }
}

// ---------------------------------------------------------------------------
// Kernel 3: exact top-NT via 4-level byte radix-select. One block per (b,h).
// Also zeroes sums[] and writes the selected-row flag array.
// ---------------------------------------------------------------------------
__global__ __launch_bounds__(256)
void topk_kernel(const float* __restrict__ m_in, int* __restrict__ m_top,
                 float* __restrict__ sums, int* __restrict__ flags, int NT)
{
    __shared__ unsigned hist[256];
    __shared__ unsigned sfx[257];
    __shared__ int sh_b, sh_rem;
    __shared__ int cnt_gt, cnt_eq;
    __shared__ int eqlist[128];

    const float* m = m_in + (size_t)blockIdx.x * L;
    const int tid = threadIdx.x;
    int* out = m_top + blockIdx.x * NT;
    int* fl  = flags + (size_t)blockIdx.x * L;

    if (tid < NT) sums[blockIdx.x * NT + tid] = 0.f;
    for (int i = tid; i < L; i += 256) fl[i] = 0;

    unsigned uv[16];
    #pragma unroll
    for (int k = 0; k < 16; k++) {
        const float f = m[tid + k * 256];
        const unsigned x = __float_as_uint(f);
        uv[k] = (x & 0x80000000u) ? ~x : (x | 0x80000000u);
    }

    unsigned prefix = 0;
    int rem = NT;

    for (int level = 0; level < 4; level++) {
        const int shift = 24 - level * 8;
        hist[tid] = 0;
        if (tid == 0) { cnt_gt = 0; cnt_eq = 0; }
        __syncthreads();
        #pragma unroll
        for (int k = 0; k < 16; k++) {
            const bool part = (level == 0) || ((uv[k] >> (shift + 8)) == prefix);
            if (part) atomicAdd(&hist[(uv[k] >> shift) & 255], 1u);
        }
        __syncthreads();
        if (tid < 64) {
            const unsigned s0 = hist[4*tid+0], s1 = hist[4*tid+1];
            const unsigned s2 = hist[4*tid+2], s3 = hist[4*tid+3];
            const unsigned loc = s0 + s1 + s2 + s3;
            unsigned suf = loc;
            #pragma unroll
            for (int off = 1; off < 64; off <<= 1) {
                const unsigned t = __shfl_down(suf, off, 64);
                if (tid + off < 64) suf += t;
            }
            const unsigned tail = suf - loc;
            sfx[4*tid+3] = tail + s3;
            sfx[4*tid+2] = tail + s3 + s2;
            sfx[4*tid+1] = tail + s3 + s2 + s1;
            sfx[4*tid+0] = suf;
            if (tid == 0) sfx[256] = 0;
        }
        __syncthreads();
        if (sfx[tid + 1] < (unsigned)rem && (unsigned)rem <= sfx[tid]) {
            sh_b   = tid;
            sh_rem = rem - (int)sfx[tid + 1];
        }
        __syncthreads();
        prefix = (prefix << 8) | (unsigned)sh_b;
        rem    = sh_rem;
        __syncthreads();
    }

    const unsigned T = prefix;
    const int n_gt = NT - rem;

    #pragma unroll
    for (int k = 0; k < 16; k++) {
        if (uv[k] > T) {
            const int pos = atomicAdd(&cnt_gt, 1);
            out[pos] = tid + k * 256;
        } else if (uv[k] == T) {
            const int pos = atomicAdd(&cnt_eq, 1);
            if (pos < 128) eqlist[pos] = tid + k * 256;
        }
    }
    __syncthreads();
    if (tid == 0) {
        int n = cnt_eq < 128 ? cnt_eq : 128;
        for (int r = 0; r < rem; r++) {
            int best = 0x7fffffff, bi = 0;
            for (int i = 0; i < n; i++)
                if (eqlist[i] < best) { best = eqlist[i]; bi = i; }
            out[n_gt + r] = best;
            eqlist[bi] = 0x7fffffff;
        }
    }
    __syncthreads();
    if (tid < NT) fl[out[tid]] = 1;
}

// ---------------------------------------------------------------------------
// Fused: blocks [0,256) = cumsum_write; [256, 256+384) = attn_scores+PV.
// FUSION: e-values stay in LDS (sE[15][512]) instead of a 12 MB global
// scores round-trip; each block computes its P.V partial in-block (wave w
// owns j-slice [w*128,+128), vreg[64] chunks, a[15] static accumulators)
// and writes pv_part[jseg][bh][u][d] / esum_part[jseg][bh][u] with PLAIN
// stores (each slot owned by exactly one block -- no atomics, no zeroing).
// Replaces attn_wv's 1.5M deep atomics + 12 MB scores write + ~64 MB read.
// ---------------------------------------------------------------------------
__global__ __launch_bounds__(256)
void k_cumsum_scores(const float* __restrict__ V, const float* __restrict__ partial,
                     const int* __restrict__ flags, float* __restrict__ out,
                     const float* __restrict__ Q, const float* __restrict__ K,
                     const int* __restrict__ m_top, float* __restrict__ pv_part,
                     float* __restrict__ esum_part, int NT)
{
    const int tid = threadIdx.x;
    if (blockIdx.x < 256) {
        const int bid = blockIdx.x;
        const int c  = (bid & 15) * 4 + (tid >> 6);
        const int h  = (bid >> 4) & (H - 1);
        const int b  = bid >> 7;
        const int d  = tid & 63;
        const size_t off = (size_t)b * L * D + h * DH + d + (size_t)(c * CH) * D;
        const float* base  = V   + off;
        float*       obase = out + off;
        const float* pb = partial + (size_t)((b * H + h) * 64) * DH + d;
        const int*   fp = flags + (size_t)(b * H + h) * L + c * CH;

        float vals[CH];
        #pragma unroll
        for (int i = 0; i < CH; i++) vals[i] = base[(size_t)i * D];

        float acc = 0.f;
        for (int cc = 0; cc < c; cc++) acc += pb[cc * DH];

        #pragma unroll
        for (int i = 0; i < CH; i++) {
            acc += vals[i];
            obase[(size_t)i * D] = fp[i] ? 0.f : acc;
        }
    } else {
        __shared__ float qsh[15][DH];
        __shared__ int   psh[15];
        __shared__ float sE[15][512];        // e-values, replaces global scores
        __shared__ float sPV[4][15 * 64];    // per-wave PV partials
        __shared__ float sES[15][4];         // per-wave e-sums

        const int rem2 = blockIdx.x - 256;   // 0..383
        const int bh = rem2 / 24;
        const int r2 = rem2 % 24;
        const int ug = r2 >> 3;              // 0..2
        const int jc = r2 & 7;               // jseg 0..7
        const int h  = bh & (H - 1);
        const int b  = bh >> 3;
        const int j0 = jc * 512;
        const int lane = tid & 63;
        const int w    = tid >> 6;

        for (int i = tid; i < 15 * DH; i += 256) {
            const int u = i >> 6, d = i & 63;
            const int p = m_top[bh * NT + ug * 15 + u];
            if (d == 0) psh[u] = p;
            qsh[u][d] = Q[((size_t)b * L + p) * D + h * DH + d];
        }
        __syncthreads();

        const float* Kb = K + (size_t)b * L * D + h * DH;
        const int ja = j0 + tid;
        const int jb = ja + 256;
        float4 k0[16], k1[16];
        {
            const float4* ra = (const float4*)(Kb + (size_t)ja * D);
            const float4* rb = (const float4*)(Kb + (size_t)jb * D);
            #pragma unroll
            for (int i = 0; i < 16; i++) { k0[i] = ra[i]; k1[i] = rb[i]; }
        }

        for (int u = 0; u < 15; u++) {
            const int p = psh[u];
            const float4* qv = (const float4*)qsh[u];
            float d0 = 0.f, d1 = 0.f;
            #pragma unroll
            for (int i = 0; i < 16; i++) {
                const float4 q4 = qv[i];
                d0 += q4.x * k0[i].x + q4.y * k0[i].y + q4.z * k0[i].z + q4.w * k0[i].w;
                d1 += q4.x * k1[i].x + q4.y * k1[i].y + q4.z * k1[i].z + q4.w * k1[i].w;
            }
            const float e0 = (ja <= p) ? __expf(d0 * 0.125f) : 0.f;
            const float e1 = (jb <= p) ? __expf(d1 * 0.125f) : 0.f;
            sE[u][tid]       = e0;
            sE[u][tid + 256] = e1;
            float t = e0 + e1;
            #pragma unroll
            for (int off = 32; off; off >>= 1) t += __shfl_xor(t, off, 64);
            if (lane == 0) sES[u][w] = t;
        }
        __syncthreads();

        if (tid < 15)
            esum_part[((size_t)jc * BH + bh) * NT + ug * 15 + tid] =
                sES[tid][0] + sES[tid][1] + sES[tid][2] + sES[tid][3];

        // ---- PV: wave w owns j-rel slice [w*128, w*128+128)
        const float* Vb = V + (size_t)b * L * D + h * DH + lane;
        float a[15];
        #pragma unroll
        for (int u = 0; u < 15; u++) a[u] = 0.f;

        #pragma unroll
        for (int ck = 0; ck < 2; ck++) {
            const int jr = w * 128 + ck * 64;
            float vreg[64];
            #pragma unroll
            for (int i = 0; i < 64; i++)
                vreg[i] = Vb[(size_t)(j0 + jr + i) * D];
            #pragma unroll
            for (int u = 0; u < 15; u++) {
                float au = a[u];
                #pragma unroll
                for (int i = 0; i < 64; i++)
                    au += sE[u][jr + i] * vreg[i];
                a[u] = au;
            }
        }
        #pragma unroll
        for (int u = 0; u < 15; u++) sPV[w][u * 64 + lane] = a[u];
        __syncthreads();

        float* pvb = pv_part + (((size_t)jc * BH + bh) * NT + (size_t)ug * 15) * 64;
        for (int i = tid; i < 15 * 64; i += 256)
            pvb[i] = sPV[0][i] + sPV[1][i] + sPV[2][i] + sPV[3][i];
    }
}

// ---------------------------------------------------------------------------
// Kernel 6: finalize -- out[p] = (sum_js pv_part) / (sum_js esum_part).
// Plain store into the rows cumsum_write zeroed (stream-ordered after it).
// ---------------------------------------------------------------------------
__global__ __launch_bounds__(256)
void k_finalize(const float* __restrict__ pv_part, const float* __restrict__ esum_part,
                const int* __restrict__ m_top, float* __restrict__ out, int NT)
{
    const int tid = threadIdx.x;
    const int g = blockIdx.x * 4 + (tid >> 6);   // (bh,u) pair index
    if (g >= BH * NT) return;
    const int d  = tid & 63;
    const int bh = g / NT;
    const int u  = g % NT;
    const int h = bh & (H - 1), b = bh >> 3;
    const int p = m_top[bh * NT + u];

    float v = 0.f, s = 0.f;
    #pragma unroll
    for (int js = 0; js < 8; js++) {
        v += pv_part[(((size_t)js * BH + bh) * NT + u) * 64 + d];
        s += esum_part[((size_t)js * BH + bh) * NT + u];
    }
    out[((size_t)b * L + p) * D + h * DH + d] = v / s;
}

// ---------------------------------------------------------------------------
extern "C" void kernel_launch(void* const* d_in, const int* in_sizes, int n_in,
                              void* d_out, int out_size, void* d_ws, size_t ws_size,
                              hipStream_t stream)
{
    const float* queries = (const float*)d_in[0];
    const float* keys    = (const float*)d_in[1];
    const float* values  = (const float*)d_in[2];
    const float* Wq      = (const float*)d_in[3];
    const float* bq      = (const float*)d_in[4];
    const float* Wk      = (const float*)d_in[5];
    const float* bk      = (const float*)d_in[6];
    const float* Wv      = (const float*)d_in[7];
    const float* bv      = (const float*)d_in[8];
    const int*   idx     = (const int*)d_in[9];
    float* out = (float*)d_out;

    const int S  = in_sizes[9] / L;   // sample_k = 45
    const int NT = S;

    const size_t NE = (size_t)B * L * D;
    float* Qb      = (float*)d_ws;
    float* Kb      = Qb + NE;
    float* Vb      = Kb + NE;
    float* m_buf   = Vb + NE;                           // BH*L
    float* cs_part = m_buf + (size_t)BH * L;            // BH*64*DH
    int*   m_top   = (int*)(cs_part + (size_t)BH * 64 * DH);
    float* sums    = (float*)(m_top + 1024);            // BH*NT (legacy, zeroed by topk)
    int*   flags   = (int*)(sums + 1024);               // BH*L
    float* pv_part = (float*)(flags + (size_t)BH * L);  // 8*BH*NT*64  (in old scores region)
    float* esum_part = pv_part + (size_t)8 * BH * NT * DH;  // 8*BH*NT
    unsigned short* Xp  = (unsigned short*)(pv_part + (size_t)BH * NT * L);  // offset unchanged
    unsigned short* WpT = Xp + (size_t)3 * 8192 * XPW;  // 3*512*K3

    k_split<<<192 + 3 * 8192 * 128 / 256, 256, 0, stream>>>(
        queries, keys, values, Wq, Wk, Wv, Xp, WpT);

    gemm_mfma<<<dim3(8192 / 128, 512 / 128, 3), 256, 0, stream>>>(
        Xp, WpT, bq, bk, bv, Qb, Kb, Vb);

    k_sample_chunks<<<256 + BH * L / 4, 256, 0, stream>>>(
        Qb, Kb, idx, m_buf, S, Vb, cs_part);

    topk_kernel<<<BH, 256, 0, stream>>>(m_buf, m_top, sums, flags, NT);

    k_cumsum_scores<<<256 + 384, 256, 0, stream>>>(
        Vb, cs_part, flags, out, Qb, Kb, m_top, pv_part, esum_part, NT);

    k_finalize<<<(BH * NT + 3) / 4, 256, 0, stream>>>(
        pv_part, esum_part, m_top, out, NT);
}